// Round 10
// baseline (898.350 us; speedup 1.0000x reference)
//
#include <hip/hip_runtime.h>
#include <hip/hip_bf16.h>
#include <math.h>

#define LSEQ 2048
#define BREAL 4
#define BT 8           // both directions batched: 4 fwd + 4 bwd(flipped)
#define DM 256
#define DI 512
#define DSZ 128        // state dim N
#define NHEADS 8
#define HDIM 64
#define DXBC 768
#define DINP 1288
#define NINP_PAD 1408  // 11*128
#define NLAYERS 4
#define QCH 64         // scan chunk length
#define NCH (LSEQ/QCH) // 32
#define CTL 64         // conv timestep tile
#define EPSF 1e-5f

typedef __attribute__((ext_vector_type(8))) short short8b;
typedef __attribute__((ext_vector_type(4))) float f32x4;

__device__ __forceinline__ float siluf(float x){ return x / (1.f + __expf(-x)); }
__device__ __forceinline__ unsigned short f2bf(float x){
    union { float f; unsigned u; } c; c.f = x;
    unsigned r = (c.u + 0x7FFFu + ((c.u >> 16) & 1u)) >> 16;
    return (unsigned short)r;
}
__device__ __forceinline__ float bf2f(unsigned short u){
    union { unsigned u; float f; } c; c.u = ((unsigned)u) << 16;
    return c.f;
}

// ---------------- prep: build batched (fwd + flipped bwd) residual stream ----------------
__global__ __launch_bounds__(256) void k_prep(const float* __restrict__ x, float* __restrict__ res){
    int i = blockIdx.x*256 + threadIdx.x;
    int d4 = i & (DM/4 - 1);
    int t  = i >> 6;
    int l  = t % LSEQ;
    int b  = t / LSEQ;
    const float4* x4 = (const float4*)x;
    float4 v;
    if (b < BREAL) v = x4[((size_t)(b*LSEQ) + l)*(DM/4) + d4];
    else           v = x4[((size_t)((b-BREAL)*LSEQ) + (LSEQ-1-l))*(DM/4) + d4];
    ((float4*)res)[i] = v;
}

// ---------------- weight transpose + fp32->bf16 convert: WT[g][n][k] = W[g][k][n] ----------------
__global__ __launch_bounds__(256) void k_wtrans(const float* __restrict__ W, unsigned short* __restrict__ WT,
                                                int K, int N, int Npad){
    __shared__ float sT[32][33];
    int n0 = blockIdx.x*32, k0 = blockIdx.y*32, g = blockIdx.z;
    const float* Wg = W + (size_t)g*K*N;
    unsigned short* WTg = WT + (size_t)g*Npad*K;
    int t = threadIdx.x;
    int r = t >> 3, c4 = (t & 7)*4;
    float4 v;
    if (n0 + c4 + 3 < N) v = *(const float4*)(Wg + (size_t)(k0+r)*N + n0 + c4);
    else {
        float tmp[4];
        #pragma unroll
        for (int j = 0; j < 4; j++) tmp[j] = (n0 + c4 + j < N) ? Wg[(size_t)(k0+r)*N + n0 + c4 + j] : 0.f;
        v = make_float4(tmp[0],tmp[1],tmp[2],tmp[3]);
    }
    sT[c4+0][r] = v.x; sT[c4+1][r] = v.y; sT[c4+2][r] = v.z; sT[c4+3][r] = v.w;
    __syncthreads();
    ushort4 o;
    o.x = f2bf(sT[r][c4+0]); o.y = f2bf(sT[r][c4+1]); o.z = f2bf(sT[r][c4+2]); o.w = f2bf(sT[r][c4+3]);
    *(ushort4*)(WTg + (size_t)(n0+r)*K + k0 + c4) = o;
}

// ---------------- rmsnorm(RES) -> u (bf16); RES is maintained by out_proj ----------------
__global__ __launch_bounds__(256) void k_resnorm(const float* __restrict__ res,
                                                 const float* __restrict__ nw, int li,
                                                 unsigned short* __restrict__ u){
    int wid  = (blockIdx.x*256 + threadIdx.x) >> 6;
    int lane = threadIdx.x & 63;
    int b = wid / LSEQ;
    const float* rr = res + (size_t)wid*DM;
    float4 v = ((const float4*)rr)[lane];
    float ss = v.x*v.x + v.y*v.y + v.z*v.z + v.w*v.w;
    #pragma unroll
    for (int o = 32; o >= 1; o >>= 1) ss += __shfl_xor(ss, o, 64);
    float sc = rsqrtf(ss*(1.f/DM) + EPSF);
    int blk = (b < BREAL) ? li : li + NLAYERS;
    float4 w = ((const float4*)(nw + (size_t)blk*DM))[lane];
    ushort4 o4;
    o4.x = f2bf(v.x*sc*w.x); o4.y = f2bf(v.y*sc*w.y); o4.z = f2bf(v.z*sc*w.z); o4.w = f2bf(v.w*sc*w.w);
    *(ushort4*)(u + (size_t)wid*DM + lane*4) = o4;
}

// ---------------- bf16 MFMA GEMM (128x128, 4 waves, BK=64, reg-prefetch, XCD swizzle) ----------------
// mode 0 = f32 store, 1 = bf16 store, 2 = f32 RMW (residual +=)
__global__ __launch_bounds__(256) void k_gemm_mfma(const unsigned short* __restrict__ A,
                                                   const unsigned short* __restrict__ WT,
                                                   int K, int N, size_t wt_group_stride, int rows_per_group,
                                                   float* __restrict__ Cf, unsigned short* __restrict__ Cb,
                                                   int mode){
    __shared__ unsigned short sA[128][72];   // stride 36 banks (= 4 mod 32): pure 2-way (free) on 16B r/w
    __shared__ unsigned short sW[128][72];
    // bijective XCD swizzle (requires nwg % 8 == 0, true for all our grids)
    int nwg = gridDim.x*gridDim.y;
    int bid = blockIdx.y*gridDim.x + blockIdx.x;
    int q = nwg >> 3;
    int xcd = bid & 7, local = bid >> 3;
    int nid = xcd*q + local;
    int bn = nid % gridDim.x;
    int bm = nid / gridDim.x;
    int row0 = bm*128, n0 = bn*128;
    const unsigned short* WTg = WT + (size_t)(row0 / rows_per_group) * wt_group_stride;
    int t = threadIdx.x;
    int w = t >> 6, lane = t & 63;
    int wr = w >> 1, wc = w & 1;
    int l15 = lane & 15, lg = lane >> 4;
    f32x4 acc[4][4];
    #pragma unroll
    for (int mi = 0; mi < 4; mi++)
        #pragma unroll
        for (int ni = 0; ni < 4; ni++) acc[mi][ni] = (f32x4){0.f,0.f,0.f,0.f};

    // staging geometry: per K-tile (64 wide) each thread moves 4 int4 of A and 4 of W.
    // element e = t + 256*i -> row = 32*i + (t>>3), col = (t&7)*8  (128 rows x 8 int4)
    int srow = t >> 3, scol = (t & 7)*8;
    const unsigned short* Ap = A + (size_t)(row0 + srow)*K + scol;
    const unsigned short* Wp = WTg + (size_t)(n0 + srow)*K + scol;

    // prefetch first K-tile into registers
    int4 ar[4], wv[4];
    #pragma unroll
    for (int i = 0; i < 4; i++){
        ar[i] = *(const int4*)(Ap + (size_t)i*32*K);
        wv[i] = *(const int4*)(Wp + (size_t)i*32*K);
    }

    for (int k0 = 0; k0 < K; k0 += 64){
        __syncthreads();
        #pragma unroll
        for (int i = 0; i < 4; i++){
            *(int4*)&sA[32*i + srow][scol] = ar[i];
            *(int4*)&sW[32*i + srow][scol] = wv[i];
        }
        __syncthreads();
        // issue next-tile loads early; they overlap with the 32 MFMAs below
        int kn = (k0 + 64 < K) ? k0 + 64 : 0;
        #pragma unroll
        for (int i = 0; i < 4; i++){
            ar[i] = *(const int4*)(Ap + kn + (size_t)i*32*K);
            wv[i] = *(const int4*)(Wp + kn + (size_t)i*32*K);
        }
        #pragma unroll
        for (int kk = 0; kk < 2; kk++){
            short8b af[4], bf[4];
            #pragma unroll
            for (int mi = 0; mi < 4; mi++) af[mi] = *(const short8b*)&sA[wr*64 + mi*16 + l15][kk*32 + lg*8];
            #pragma unroll
            for (int ni = 0; ni < 4; ni++) bf[ni] = *(const short8b*)&sW[wc*64 + ni*16 + l15][kk*32 + lg*8];
            #pragma unroll
            for (int mi = 0; mi < 4; mi++)
                #pragma unroll
                for (int ni = 0; ni < 4; ni++)
                    acc[mi][ni] = __builtin_amdgcn_mfma_f32_16x16x32_bf16(af[mi], bf[ni], acc[mi][ni], 0, 0, 0);
        }
    }
    #pragma unroll
    for (int mi = 0; mi < 4; mi++)
        #pragma unroll
        for (int ni = 0; ni < 4; ni++){
            int col = n0 + wc*64 + ni*16 + l15;
            if (col < N){
                #pragma unroll
                for (int r = 0; r < 4; r++){
                    int row = row0 + wr*64 + mi*16 + lg*4 + r;
                    if (mode == 1)      Cb[(size_t)row*N + col] = f2bf(acc[mi][ni][r]);
                    else if (mode == 2) Cf[(size_t)row*N + col] += acc[mi][ni][r];
                    else                Cf[(size_t)row*N + col] = acc[mi][ni][r];
                }
            }
        }
}

// ---------------- causal dwconv(K=4)+silu sliding-window + fused dt softplus/log-decay ----------------
__global__ __launch_bounds__(256) void k_conv2(const unsigned short* __restrict__ zxb,
                                               const float* __restrict__ cw, const float* __restrict__ cb,
                                               const float* __restrict__ dtb, const float* __restrict__ Al,
                                               int li, unsigned short* __restrict__ xbcb,
                                               float* __restrict__ dtO, float* __restrict__ laO){
    int bid = blockIdx.x;                 // BT * (LSEQ/CTL) * 3
    int ch = bid % 3;
    int tl = (bid/3) % (LSEQ/CTL);
    int b  = bid / (3*(LSEQ/CTL));
    int c  = ch*256 + threadIdx.x;
    int blk = (b < BREAL) ? li : li + NLAYERS;
    float4 wv = *(const float4*)(cw + (size_t)blk*DXBC*4 + c*4);
    float bias = cb[(size_t)blk*DXBC + c];
    int l0 = tl*CTL;
    size_t base = ((size_t)b*LSEQ)*DINP + DI + c;
    float xm3 = (l0 >= 3) ? bf2f(zxb[base + (size_t)(l0-3)*DINP]) : 0.f;
    float xm2 = (l0 >= 2) ? bf2f(zxb[base + (size_t)(l0-2)*DINP]) : 0.f;
    float xm1 = (l0 >= 1) ? bf2f(zxb[base + (size_t)(l0-1)*DINP]) : 0.f;
    for (int l = l0; l < l0 + CTL; l++){
        float xv = bf2f(zxb[base + (size_t)l*DINP]);
        float acc = bias + xm3*wv.x + xm2*wv.y + xm1*wv.z + xv*wv.w;
        xbcb[((size_t)(b*LSEQ)+l)*DXBC + c] = f2bf(siluf(acc));
        xm3 = xm2; xm2 = xm1; xm1 = xv;
    }
    if (ch == 0){
        #pragma unroll
        for (int it = 0; it < 2; it++){
            int e = threadIdx.x*2 + it;        // 0..511 = CTL x NHEADS
            int h = e & 7, dl = e >> 3;
            size_t bl = (size_t)b*LSEQ + l0 + dl;
            float raw = bf2f(zxb[bl*DINP + DI + DXBC + h]) + dtb[blk*NHEADS + h];
            float d = (raw > 20.f) ? raw : log1pf(__expf(raw));
            dtO[bl*NHEADS + h] = d;
            laO[bl*NHEADS + h] = -d*__expf(Al[blk*NHEADS + h]);
        }
    }
}

// ---------------- chunk pass 1 (MFMA, 4 heads/block): h_loc = (w*dt*x)^T @ B ----------------
__global__ __launch_bounds__(256) void k_chunk_state(const unsigned short* __restrict__ xbcb,
                                                     const float* __restrict__ dt, const float* __restrict__ la,
                                                     unsigned short* __restrict__ states, float* __restrict__ decp){
    __shared__ unsigned short sBT[DSZ][72];   // B^T: [n][j]
    __shared__ unsigned short sXT[HDIM][72];  // (dt*x*w)^T: [p][j]  (per-head, reused)
    __shared__ float sW[4][QCH];
    int bid = blockIdx.x;                     // BT*NCH*2
    int hg = bid & 1;
    int c  = (bid >> 1) & (NCH-1);
    int b  = bid >> 6;
    int t = threadIdx.x;
    int w = t >> 6, lane = t & 63, l15 = lane & 15, lg = lane >> 4;
    size_t bl0 = (size_t)b*LSEQ + c*QCH;

    // per-wave cumsum: wave w owns head hg*4+w
    {
        int h = hg*4 + w;
        float v = la[(bl0 + lane)*NHEADS + h];
        #pragma unroll
        for (int o = 1; o < 64; o <<= 1){
            float u = __shfl_up(v, o, 64);
            if (lane >= o) v += u;
        }
        float saQ = __shfl(v, 63, 64);
        float dtv = dt[(bl0 + lane)*NHEADS + h];
        sW[w][lane] = dtv * __expf(saQ - v);
        if (lane == 63) decp[((size_t)b*NHEADS + h)*NCH + c] = __expf(v);
    }
    // stage B^T (scatter) : 64 rows(j) x 128 cols(n) -- shared by all heads
    #pragma unroll
    for (int it = 0; it < 4; it++){
        int e = t + 256*it;
        int j = e >> 4, n8 = (e & 15)*8;
        int4 v = *(const int4*)(xbcb + (bl0 + j)*DXBC + DI + n8);
        const unsigned short* pv = (const unsigned short*)&v;
        #pragma unroll
        for (int i = 0; i < 8; i++) sBT[n8+i][j] = pv[i];
    }
    __syncthreads();

    int p0 = (w >> 1)*32, n0 = (w & 1)*64;
    for (int hh = 0; hh < 4; hh++){
        int h = hg*4 + hh;
        // stage (w*dt*x)^T for this head
        #pragma unroll
        for (int it = 0; it < 4; it++){
            int e = t + 256*it;
            int j = e >> 4, p4 = (e & 15)*4;
            ushort4 v = *(const ushort4*)(xbcb + (bl0 + j)*DXBC + h*HDIM + p4);
            float s = sW[hh][j];
            sXT[p4+0][j] = f2bf(bf2f(v.x)*s);
            sXT[p4+1][j] = f2bf(bf2f(v.y)*s);
            sXT[p4+2][j] = f2bf(bf2f(v.z)*s);
            sXT[p4+3][j] = f2bf(bf2f(v.w)*s);
        }
        __syncthreads();
        f32x4 acc[2][4];
        #pragma unroll
        for (int mi = 0; mi < 2; mi++)
            #pragma unroll
            for (int ni = 0; ni < 4; ni++) acc[mi][ni] = (f32x4){0.f,0.f,0.f,0.f};
        #pragma unroll
        for (int kk = 0; kk < 2; kk++){
            short8b a[2], bb[4];
            #pragma unroll
            for (int mi = 0; mi < 2; mi++) a[mi]  = *(const short8b*)&sXT[p0 + mi*16 + l15][kk*32 + lg*8];
            #pragma unroll
            for (int ni = 0; ni < 4; ni++) bb[ni] = *(const short8b*)&sBT[n0 + ni*16 + l15][kk*32 + lg*8];
            #pragma unroll
            for (int mi = 0; mi < 2; mi++)
                #pragma unroll
                for (int ni = 0; ni < 4; ni++)
                    acc[mi][ni] = __builtin_amdgcn_mfma_f32_16x16x32_bf16(a[mi], bb[ni], acc[mi][ni], 0, 0, 0);
        }
        unsigned short* sp = states + (((size_t)b*NHEADS + h)*NCH + c)*(HDIM*DSZ);
        #pragma unroll
        for (int mi = 0; mi < 2; mi++)
            #pragma unroll
            for (int ni = 0; ni < 4; ni++)
                #pragma unroll
                for (int r = 0; r < 4; r++){
                    int p = p0 + mi*16 + lg*4 + r;
                    int n = n0 + ni*16 + l15;
                    sp[(size_t)p*DSZ + n] = f2bf(acc[mi][ni][r]);
                }
        __syncthreads();
    }
}

// ---------------- pass 2: sequential combine across chunks (bf16 storage, f32 accum) ----------------
__global__ __launch_bounds__(256) void k_scan2(unsigned short* __restrict__ states, const float* __restrict__ decp){
    int bh = blockIdx.x >> 3, slice = blockIdx.x & 7;
    int t = threadIdx.x;
    size_t base = (size_t)bh*NCH*(HDIM*DSZ) + slice*1024 + t*4;
    float H0=0.f, H1=0.f, H2=0.f, H3=0.f;
    for (int c = 0; c < NCH; c++){
        float P = decp[bh*NCH + c];
        unsigned short* sp = states + base + (size_t)c*(HDIM*DSZ);
        ushort4 S = *(ushort4*)sp;
        ushort4 Hw;
        Hw.x = f2bf(H0); Hw.y = f2bf(H1); Hw.z = f2bf(H2); Hw.w = f2bf(H3);
        *(ushort4*)sp = Hw;
        H0 = fmaf(H0, P, bf2f(S.x));
        H1 = fmaf(H1, P, bf2f(S.y));
        H2 = fmaf(H2, P, bf2f(S.z));
        H3 = fmaf(H3, P, bf2f(S.w));
    }
}

// ---------------- chunk pass 3 (MFMA, 4 heads/block): Y = mask(C@B^T)@dtX + diag(exp(sa))*(C@h^T) + D*x ----------------
__global__ __launch_bounds__(256) void k_chunk_y(const unsigned short* __restrict__ xbcb,
                                                 const float* __restrict__ dt, const float* __restrict__ la,
                                                 const unsigned short* __restrict__ states,
                                                 const float* __restrict__ Dp, int li,
                                                 unsigned short* __restrict__ y){
    __shared__ unsigned short sB_[QCH][136];   // B rows [j][n] (shared across heads)
    __shared__ unsigned short sC_[QCH][136];   // C rows [i][n] (shared across heads)
    __shared__ unsigned short sS[QCH][72];     // masked S [i][j] (per-head)
    __shared__ unsigned short sXT[HDIM][72];   // (dt*x)^T [p][j] (per-head)
    __shared__ unsigned short sH[HDIM][136];   // h_in rows [p][n] (per-head)
    __shared__ float sSa[4][QCH];
    __shared__ float sDt[4][QCH];
    int bid = blockIdx.x;                      // BT*NCH*2
    int hg = bid & 1;
    int c  = (bid >> 1) & (NCH-1);
    int b  = bid >> 6;
    int blk = (b < BREAL) ? li : li + NLAYERS;
    int t = threadIdx.x;
    int w = t >> 6, lane = t & 63, l15 = lane & 15, lg = lane >> 4;
    size_t bl0 = (size_t)b*LSEQ + c*QCH;

    // per-wave cumsum: wave w owns head hg*4+w
    {
        int h = hg*4 + w;
        float v = la[(bl0 + lane)*NHEADS + h];
        #pragma unroll
        for (int o = 1; o < 64; o <<= 1){
            float u = __shfl_up(v, o, 64);
            if (lane >= o) v += u;
        }
        sSa[w][lane] = v;
        sDt[w][lane] = dt[(bl0 + lane)*NHEADS + h];
    }
    // stage B, C rows (shared)
    #pragma unroll
    for (int it = 0; it < 4; it++){
        int e = t + 256*it;
        int j = e >> 4, n8 = (e & 15)*8;
        *(int4*)&sB_[j][n8] = *(const int4*)(xbcb + (bl0 + j)*DXBC + DI + n8);
        *(int4*)&sC_[j][n8] = *(const int4*)(xbcb + (bl0 + j)*DXBC + DI + DSZ + n8);
    }
    __syncthreads();

    int i0 = (w >> 1)*32, q0 = (w & 1)*32;

    // SRAW = C @ B^T (K=128) once; persists in registers across head loop
    f32x4 accS[2][2];
    #pragma unroll
    for (int mi = 0; mi < 2; mi++)
        #pragma unroll
        for (int nj = 0; nj < 2; nj++) accS[mi][nj] = (f32x4){0.f,0.f,0.f,0.f};
    #pragma unroll
    for (int kk = 0; kk < 4; kk++){
        short8b a[2], bb[2];
        #pragma unroll
        for (int mi = 0; mi < 2; mi++) a[mi]  = *(const short8b*)&sC_[i0 + mi*16 + l15][kk*32 + lg*8];
        #pragma unroll
        for (int nj = 0; nj < 2; nj++) bb[nj] = *(const short8b*)&sB_[q0 + nj*16 + l15][kk*32 + lg*8];
        #pragma unroll
        for (int mi = 0; mi < 2; mi++)
            #pragma unroll
            for (int nj = 0; nj < 2; nj++)
                accS[mi][nj] = __builtin_amdgcn_mfma_f32_16x16x32_bf16(a[mi], bb[nj], accS[mi][nj], 0, 0, 0);
    }

    for (int hh = 0; hh < 4; hh++){
        int h = hg*4 + hh;
        // mask SRAW with per-head decay -> sS (bf16)
        #pragma unroll
        for (int mi = 0; mi < 2; mi++)
            #pragma unroll
            for (int nj = 0; nj < 2; nj++)
                #pragma unroll
                for (int r = 0; r < 4; r++){
                    int i = i0 + mi*16 + lg*4 + r;
                    int j = q0 + nj*16 + l15;
                    float wgt = (i >= j) ? __expf(sSa[hh][i] - sSa[hh][j]) : 0.f;
                    sS[i][j] = f2bf(accS[mi][nj][r] * wgt);
                }
        // stage (dt*x)^T and h_in for this head
        #pragma unroll
        for (int it = 0; it < 4; it++){
            int e = t + 256*it;
            int j = e >> 4, p4 = (e & 15)*4;
            ushort4 v = *(const ushort4*)(xbcb + (bl0 + j)*DXBC + h*HDIM + p4);
            float s = sDt[hh][j];
            sXT[p4+0][j] = f2bf(bf2f(v.x)*s);
            sXT[p4+1][j] = f2bf(bf2f(v.y)*s);
            sXT[p4+2][j] = f2bf(bf2f(v.z)*s);
            sXT[p4+3][j] = f2bf(bf2f(v.w)*s);
        }
        {
            size_t sbase = (((size_t)b*NHEADS + h)*NCH + c)*(HDIM*DSZ);
            #pragma unroll
            for (int it = 0; it < 4; it++){
                int e = t + 256*it;
                int p = e >> 4, n8 = (e & 15)*8;
                *(int4*)&sH[p][n8] = *(const int4*)(states + sbase + (size_t)p*DSZ + n8);
            }
        }
        __syncthreads();

        // Y_intra = S @ dtX (K=64); Y_inter = C @ h^T (K=128)
        f32x4 accY[2][2], accI[2][2];
        #pragma unroll
        for (int mi = 0; mi < 2; mi++)
            #pragma unroll
            for (int nj = 0; nj < 2; nj++){ accY[mi][nj] = (f32x4){0.f,0.f,0.f,0.f}; accI[mi][nj] = (f32x4){0.f,0.f,0.f,0.f}; }
        #pragma unroll
        for (int kk = 0; kk < 2; kk++){
            short8b a[2], bb[2];
            #pragma unroll
            for (int mi = 0; mi < 2; mi++) a[mi]  = *(const short8b*)&sS[i0 + mi*16 + l15][kk*32 + lg*8];
            #pragma unroll
            for (int nj = 0; nj < 2; nj++) bb[nj] = *(const short8b*)&sXT[q0 + nj*16 + l15][kk*32 + lg*8];
            #pragma unroll
            for (int mi = 0; mi < 2; mi++)
                #pragma unroll
                for (int nj = 0; nj < 2; nj++)
                    accY[mi][nj] = __builtin_amdgcn_mfma_f32_16x16x32_bf16(a[mi], bb[nj], accY[mi][nj], 0, 0, 0);
        }
        #pragma unroll
        for (int kk = 0; kk < 4; kk++){
            short8b a[2], bb[2];
            #pragma unroll
            for (int mi = 0; mi < 2; mi++) a[mi]  = *(const short8b*)&sC_[i0 + mi*16 + l15][kk*32 + lg*8];
            #pragma unroll
            for (int nj = 0; nj < 2; nj++) bb[nj] = *(const short8b*)&sH[q0 + nj*16 + l15][kk*32 + lg*8];
            #pragma unroll
            for (int mi = 0; mi < 2; mi++)
                #pragma unroll
                for (int nj = 0; nj < 2; nj++)
                    accI[mi][nj] = __builtin_amdgcn_mfma_f32_16x16x32_bf16(a[mi], bb[nj], accI[mi][nj], 0, 0, 0);
        }

        float dD = Dp[blk*NHEADS + h];
        #pragma unroll
        for (int mi = 0; mi < 2; mi++)
            #pragma unroll
            for (int r = 0; r < 4; r++){
                int i = i0 + mi*16 + lg*4 + r;
                float ei = __expf(sSa[hh][i]);
                #pragma unroll
                for (int nj = 0; nj < 2; nj++){
                    int p = q0 + nj*16 + l15;
                    float xh = bf2f(xbcb[(bl0 + i)*DXBC + h*HDIM + p]);
                    y[(bl0 + i)*DI + h*HDIM + p] = f2bf(accY[mi][nj][r] + ei*accI[mi][nj][r] + dD*xh);
                }
            }
        __syncthreads();
    }
}

// ---------------- gated rmsnorm: g = rmsnorm(y * silu(z)) * gw -> bf16 ----------------
__global__ __launch_bounds__(256) void k_gatenorm(const unsigned short* __restrict__ y, const unsigned short* __restrict__ zxb,
                                                  const float* __restrict__ gw, int li,
                                                  unsigned short* __restrict__ yb){
    int wid  = (blockIdx.x*256 + threadIdx.x) >> 6;
    int lane = threadIdx.x & 63;
    int b = wid / LSEQ;
    int blk = (b < BREAL) ? li : li + NLAYERS;
    const unsigned short* yr = y + (size_t)wid*DI;
    const unsigned short* zr = zxb + (size_t)wid*DINP;
    ushort4 yu0 = *(const ushort4*)(yr + lane*4);
    ushort4 yu1 = *(const ushort4*)(yr + 256 + lane*4);
    ushort4 zu0 = *(const ushort4*)(zr + lane*4);
    ushort4 zu1 = *(const ushort4*)(zr + 256 + lane*4);
    float4 v0, v1;
    v0.x = bf2f(yu0.x)*siluf(bf2f(zu0.x)); v0.y = bf2f(yu0.y)*siluf(bf2f(zu0.y));
    v0.z = bf2f(yu0.z)*siluf(bf2f(zu0.z)); v0.w = bf2f(yu0.w)*siluf(bf2f(zu0.w));
    v1.x = bf2f(yu1.x)*siluf(bf2f(zu1.x)); v1.y = bf2f(yu1.y)*siluf(bf2f(zu1.y));
    v1.z = bf2f(yu1.z)*siluf(bf2f(zu1.z)); v1.w = bf2f(yu1.w)*siluf(bf2f(zu1.w));
    float ss = v0.x*v0.x + v0.y*v0.y + v0.z*v0.z + v0.w*v0.w
             + v1.x*v1.x + v1.y*v1.y + v1.z*v1.z + v1.w*v1.w;
    #pragma unroll
    for (int o = 32; o >= 1; o >>= 1) ss += __shfl_xor(ss, o, 64);
    float sc = rsqrtf(ss*(1.f/DI) + EPSF);
    const float4* w4 = (const float4*)(gw + (size_t)blk*DI);
    float4 w0 = w4[lane], w1 = w4[64 + lane];
    ushort4 o0, o1;
    o0.x = f2bf(v0.x*sc*w0.x); o0.y = f2bf(v0.y*sc*w0.y); o0.z = f2bf(v0.z*sc*w0.z); o0.w = f2bf(v0.w*sc*w0.w);
    o1.x = f2bf(v1.x*sc*w1.x); o1.y = f2bf(v1.y*sc*w1.y); o1.z = f2bf(v1.z*sc*w1.z); o1.w = f2bf(v1.w*sc*w1.w);
    *(ushort4*)(yb + (size_t)wid*DI + lane*4)       = o0;
    *(ushort4*)(yb + (size_t)wid*DI + 256 + lane*4) = o1;
}

// ---------------- final: out = RES_fwd + flip(RES_bwd) ----------------
__global__ __launch_bounds__(256) void k_final(const float* __restrict__ res, float* __restrict__ out){
    int i = blockIdx.x*256 + threadIdx.x;
    int d4 = i & 63;
    int t  = i >> 6;
    int l = t % LSEQ, b = t / LSEQ;
    size_t fi = ((size_t)(b*LSEQ) + l)*(DM/4) + d4;
    size_t bi = ((size_t)((b+BREAL)*LSEQ) + (LSEQ-1-l))*(DM/4) + d4;
    float4 r1 = ((const float4*)res)[fi];
    float4 r2 = ((const float4*)res)[bi];
    float4 o;
    o.x = r1.x + r2.x;
    o.y = r1.y + r2.y;
    o.z = r1.z + r2.z;
    o.w = r1.w + r2.w;
    ((float4*)out)[i] = o;
}

extern "C" void kernel_launch(void* const* d_in, const int* in_sizes, int n_in,
                              void* d_out, int out_size, void* d_ws, size_t ws_size,
                              hipStream_t stream){
    const float* x   = (const float*)d_in[0];
    const float* nw  = (const float*)d_in[1];
    const float* Wi  = (const float*)d_in[2];
    const float* cw  = (const float*)d_in[3];
    const float* cb  = (const float*)d_in[4];
    const float* dtb = (const float*)d_in[5];
    const float* Al  = (const float*)d_in[6];
    const float* Dp  = (const float*)d_in[7];
    const float* gw  = (const float*)d_in[8];
    const float* Wo  = (const float*)d_in[9];
    float* out = (float*)d_out;

    // ---- workspace layout (~154 MiB) ----
    size_t off = 0;
    auto alloc = [&](size_t bytes){ void* p = (char*)d_ws + off; off += (bytes + 255) & ~(size_t)255; return p; };
    float* RES    = (float*)alloc((size_t)BT*LSEQ*DM*4);                        // 16 MiB, maintained by out_proj
    unsigned short* STATES = (unsigned short*)alloc((size_t)BT*NHEADS*NCH*HDIM*DSZ*2); // 32 MiB bf16
    unsigned short* YGB = (unsigned short*)alloc((size_t)BT*LSEQ*DI*2);         // 16 MiB (UBUF aliases)
    unsigned short* UBUF = YGB;
    unsigned short* ZXB = (unsigned short*)alloc((size_t)BT*LSEQ*DINP*2);       // 40.25 MiB bf16
    unsigned short* XBC = (unsigned short*)alloc((size_t)BT*LSEQ*DXBC*2);       // 24 MiB bf16
    float* DT     = (float*)alloc((size_t)BT*LSEQ*NHEADS*4);
    float* LA     = (float*)alloc((size_t)BT*LSEQ*NHEADS*4);
    unsigned short* YG = (unsigned short*)alloc((size_t)BT*LSEQ*DI*2);          // 16 MiB bf16
    float* DECP   = (float*)alloc((size_t)BT*NHEADS*NCH*4);
    unsigned short* WiT = (unsigned short*)alloc((size_t)2*NLAYERS*NINP_PAD*DM*2); // 5.5 MiB
    unsigned short* WoT = (unsigned short*)alloc((size_t)2*NLAYERS*DM*DI*2);       // 2 MiB
    (void)ws_size; (void)in_sizes; (void)n_in; (void)out_size;

    k_prep<<<(BT*LSEQ*DM/4)/256, 256, 0, stream>>>(x, RES);
    k_wtrans<<<dim3(NINP_PAD/32, DM/32, 2*NLAYERS), 256, 0, stream>>>(Wi, WiT, DM, DINP, NINP_PAD);
    k_wtrans<<<dim3(DM/32, DI/32, 2*NLAYERS), 256, 0, stream>>>(Wo, WoT, DI, DM, DM);

    for (int li = 0; li < NLAYERS; li++){
        k_resnorm<<<(BT*LSEQ)/4, 256, 0, stream>>>(RES, nw, li, UBUF);
        // in_proj: (BT*L x 256) @ (256 x 1288) -> bf16, 128x128 tiles BK=64 (nwg = 1408, %8==0)
        k_gemm_mfma<<<dim3(NINP_PAD/128, (BT*LSEQ)/128), 256, 0, stream>>>(
            UBUF, WiT + (size_t)li*NINP_PAD*DM, DM, DINP,
            (size_t)NLAYERS*NINP_PAD*DM, BREAL*LSEQ, nullptr, ZXB, 1);
        k_conv2<<<BT*(LSEQ/CTL)*3, 256, 0, stream>>>(ZXB, cw, cb, dtb, Al, li, XBC, DT, LA);
        k_chunk_state<<<BT*NCH*2, 256, 0, stream>>>(XBC, DT, LA, STATES, DECP);
        k_scan2<<<BT*NHEADS*8, 256, 0, stream>>>(STATES, DECP);
        k_chunk_y<<<BT*NCH*2, 256, 0, stream>>>(XBC, DT, LA, STATES, Dp, li, YG);
        k_gatenorm<<<(BT*LSEQ)/4, 256, 0, stream>>>(YG, ZXB, gw, li, YGB);
        // out_proj: (BT*L x 512) @ (512 x 256), RES += result (nwg = 256, %8==0)
        k_gemm_mfma<<<dim3(DM/128, (BT*LSEQ)/128), 256, 0, stream>>>(
            YGB, WoT + (size_t)li*DM*DI, DI, DM,
            (size_t)NLAYERS*DM*DI, BREAL*LSEQ, RES, nullptr, 2);
    }
    k_final<<<(BREAL*LSEQ*DM/4)/256, 256, 0, stream>>>(RES, out);
}

// Round 12
// 680.440 us; speedup vs baseline: 1.3202x; 1.3202x over previous
//
#include <hip/hip_runtime.h>
#include <hip/hip_bf16.h>
#include <math.h>

#define LSEQ 2048
#define BREAL 4
#define BT 8           // both directions batched: 4 fwd + 4 bwd(flipped)
#define DM 256
#define DI 512
#define DSZ 128        // state dim N
#define NHEADS 8
#define HDIM 64
#define DXBC 768
#define DINP 1288
#define NINP_PAD 1408  // 11*128
#define NLAYERS 4
#define QCH 64         // scan chunk length
#define NCH (LSEQ/QCH) // 32
#define CTL 64         // conv timestep tile
#define EPSF 1e-5f

typedef __attribute__((ext_vector_type(8))) short short8b;
typedef __attribute__((ext_vector_type(4))) float f32x4;

__device__ __forceinline__ float siluf(float x){ return x / (1.f + __expf(-x)); }
__device__ __forceinline__ unsigned short f2bf(float x){
    union { float f; unsigned u; } c; c.f = x;
    unsigned r = (c.u + 0x7FFFu + ((c.u >> 16) & 1u)) >> 16;
    return (unsigned short)r;
}
__device__ __forceinline__ float bf2f(unsigned short u){
    union { unsigned u; float f; } c; c.u = ((unsigned)u) << 16;
    return c.f;
}

// ---------------- prep: build batched (fwd + flipped bwd) residual stream ----------------
__global__ __launch_bounds__(256) void k_prep(const float* __restrict__ x, float* __restrict__ res){
    int i = blockIdx.x*256 + threadIdx.x;
    int d4 = i & (DM/4 - 1);
    int t  = i >> 6;
    int l  = t % LSEQ;
    int b  = t / LSEQ;
    const float4* x4 = (const float4*)x;
    float4 v;
    if (b < BREAL) v = x4[((size_t)(b*LSEQ) + l)*(DM/4) + d4];
    else           v = x4[((size_t)((b-BREAL)*LSEQ) + (LSEQ-1-l))*(DM/4) + d4];
    ((float4*)res)[i] = v;
}

// ---------------- weight transpose + fp32->bf16 convert: WT[g][n][k] = W[g][k][n] ----------------
__global__ __launch_bounds__(256) void k_wtrans(const float* __restrict__ W, unsigned short* __restrict__ WT,
                                                int K, int N, int Npad){
    __shared__ float sT[32][33];
    int n0 = blockIdx.x*32, k0 = blockIdx.y*32, g = blockIdx.z;
    const float* Wg = W + (size_t)g*K*N;
    unsigned short* WTg = WT + (size_t)g*Npad*K;
    int t = threadIdx.x;
    int r = t >> 3, c4 = (t & 7)*4;
    float4 v;
    if (n0 + c4 + 3 < N) v = *(const float4*)(Wg + (size_t)(k0+r)*N + n0 + c4);
    else {
        float tmp[4];
        #pragma unroll
        for (int j = 0; j < 4; j++) tmp[j] = (n0 + c4 + j < N) ? Wg[(size_t)(k0+r)*N + n0 + c4 + j] : 0.f;
        v = make_float4(tmp[0],tmp[1],tmp[2],tmp[3]);
    }
    sT[c4+0][r] = v.x; sT[c4+1][r] = v.y; sT[c4+2][r] = v.z; sT[c4+3][r] = v.w;
    __syncthreads();
    ushort4 o;
    o.x = f2bf(sT[r][c4+0]); o.y = f2bf(sT[r][c4+1]); o.z = f2bf(sT[r][c4+2]); o.w = f2bf(sT[r][c4+3]);
    *(ushort4*)(WTg + (size_t)(n0+r)*K + k0 + c4) = o;
}

// ---------------- rmsnorm(RES) -> u (bf16); RES is maintained by out_proj ----------------
__global__ __launch_bounds__(256) void k_resnorm(const float* __restrict__ res,
                                                 const float* __restrict__ nw, int li,
                                                 unsigned short* __restrict__ u){
    int wid  = (blockIdx.x*256 + threadIdx.x) >> 6;
    int lane = threadIdx.x & 63;
    int b = wid / LSEQ;
    const float* rr = res + (size_t)wid*DM;
    float4 v = ((const float4*)rr)[lane];
    float ss = v.x*v.x + v.y*v.y + v.z*v.z + v.w*v.w;
    #pragma unroll
    for (int o = 32; o >= 1; o >>= 1) ss += __shfl_xor(ss, o, 64);
    float sc = rsqrtf(ss*(1.f/DM) + EPSF);
    int blk = (b < BREAL) ? li : li + NLAYERS;
    float4 w = ((const float4*)(nw + (size_t)blk*DM))[lane];
    ushort4 o4;
    o4.x = f2bf(v.x*sc*w.x); o4.y = f2bf(v.y*sc*w.y); o4.z = f2bf(v.z*sc*w.z); o4.w = f2bf(v.w*sc*w.w);
    *(ushort4*)(u + (size_t)wid*DM + lane*4) = o4;
}

// ---------------- bf16 MFMA GEMM (128x128, 4 waves, BK=32, reg-prefetch, XCD swizzle) ----------------
// mode 0 = f32 store, 1 = bf16 store via LDS-staged coalesced epilogue, 2 = f32 RMW (residual +=)
__global__ __launch_bounds__(256) void k_gemm_mfma(const unsigned short* __restrict__ A,
                                                   const unsigned short* __restrict__ WT,
                                                   int K, int N, size_t wt_group_stride, int rows_per_group,
                                                   float* __restrict__ Cf, unsigned short* __restrict__ Cb,
                                                   int mode){
    __shared__ unsigned short sA[128][42];   // stride 21 banks
    __shared__ unsigned short sW[128][42];
    __shared__ unsigned short sC[64][132];   // staged bf16 C half-tile (mode 1)
    // bijective XCD swizzle (requires nwg % 8 == 0, true for all our grids)
    int nwg = gridDim.x*gridDim.y;
    int bid = blockIdx.y*gridDim.x + blockIdx.x;
    int q = nwg >> 3;
    int xcd = bid & 7, local = bid >> 3;
    int nid = xcd*q + local;
    int bn = nid % gridDim.x;
    int bm = nid / gridDim.x;
    int row0 = bm*128, n0 = bn*128;
    const unsigned short* WTg = WT + (size_t)(row0 / rows_per_group) * wt_group_stride;
    int t = threadIdx.x;
    int w = t >> 6, lane = t & 63;
    int wr = w >> 1, wc = w & 1;
    int l15 = lane & 15, lg = lane >> 4;
    f32x4 acc[4][4];
    #pragma unroll
    for (int mi = 0; mi < 4; mi++)
        #pragma unroll
        for (int ni = 0; ni < 4; ni++) acc[mi][ni] = (f32x4){0.f,0.f,0.f,0.f};

    int srow = t >> 1, shalf = t & 1;
    const unsigned short* Ap = A + (size_t)(row0 + srow)*K + shalf*16;
    const unsigned short* Wp = WTg + (size_t)(n0 + srow)*K + shalf*16;

    // prefetch first K-tile into registers
    int4 a0 = *(const int4*)(Ap);
    int4 a1 = *(const int4*)(Ap + 8);
    int4 w0 = *(const int4*)(Wp);
    int4 w1 = *(const int4*)(Wp + 8);

    for (int k0 = 0; k0 < K; k0 += 32){
        __syncthreads();
        *(int4*)&sA[srow][shalf*16]     = a0;
        *(int4*)&sA[srow][shalf*16 + 8] = a1;
        *(int4*)&sW[srow][shalf*16]     = w0;
        *(int4*)&sW[srow][shalf*16 + 8] = w1;
        __syncthreads();
        // issue next-tile loads early; they overlap with the MFMAs below
        int kn = (k0 + 32 < K) ? k0 + 32 : 0;
        a0 = *(const int4*)(Ap + kn);
        a1 = *(const int4*)(Ap + kn + 8);
        w0 = *(const int4*)(Wp + kn);
        w1 = *(const int4*)(Wp + kn + 8);
        short8b af[4], bf[4];
        #pragma unroll
        for (int mi = 0; mi < 4; mi++) af[mi] = *(const short8b*)&sA[wr*64 + mi*16 + l15][lg*8];
        #pragma unroll
        for (int ni = 0; ni < 4; ni++) bf[ni] = *(const short8b*)&sW[wc*64 + ni*16 + l15][lg*8];
        #pragma unroll
        for (int mi = 0; mi < 4; mi++)
            #pragma unroll
            for (int ni = 0; ni < 4; ni++)
                acc[mi][ni] = __builtin_amdgcn_mfma_f32_16x16x32_bf16(af[mi], bf[ni], acc[mi][ni], 0, 0, 0);
    }
    if (mode == 1){
        // stage bf16 C through LDS in two 64-row halves -> fully coalesced int4 stores
        #pragma unroll
        for (int h = 0; h < 2; h++){
            if (wr == h){
                #pragma unroll
                for (int mi = 0; mi < 4; mi++)
                    #pragma unroll
                    for (int ni = 0; ni < 4; ni++)
                        #pragma unroll
                        for (int r = 0; r < 4; r++)
                            sC[mi*16 + lg*4 + r][wc*64 + ni*16 + l15] = f2bf(acc[mi][ni][r]);
            }
            __syncthreads();
            #pragma unroll
            for (int p = 0; p < 4; p++){
                int e = t + 256*p;          // 1024 = 64 rows x 16 int4
                int rr = e >> 4, cc = (e & 15)*8;
                int col = n0 + cc;
                if (col < N)                // N % 8 == 0 so int4 validity is all-or-nothing
                    *(int4*)(Cb + (size_t)(row0 + h*64 + rr)*N + col) = *(int4*)&sC[rr][cc];
            }
            __syncthreads();
        }
    } else {
        #pragma unroll
        for (int mi = 0; mi < 4; mi++)
            #pragma unroll
            for (int ni = 0; ni < 4; ni++){
                int col = n0 + wc*64 + ni*16 + l15;
                if (col < N){
                    #pragma unroll
                    for (int r = 0; r < 4; r++){
                        int row = row0 + wr*64 + mi*16 + lg*4 + r;
                        if (mode == 2) Cf[(size_t)row*N + col] += acc[mi][ni][r];
                        else           Cf[(size_t)row*N + col] = acc[mi][ni][r];
                    }
                }
            }
    }
}

// ---------------- causal dwconv(K=4)+silu sliding-window + fused dt softplus/log-decay ----------------
__global__ __launch_bounds__(256) void k_conv2(const unsigned short* __restrict__ zxb,
                                               const float* __restrict__ cw, const float* __restrict__ cb,
                                               const float* __restrict__ dtb, const float* __restrict__ Al,
                                               int li, unsigned short* __restrict__ xbcb,
                                               float* __restrict__ dtO, float* __restrict__ laO){
    int bid = blockIdx.x;                 // BT * (LSEQ/CTL) * 3
    int ch = bid % 3;
    int tl = (bid/3) % (LSEQ/CTL);
    int b  = bid / (3*(LSEQ/CTL));
    int c  = ch*256 + threadIdx.x;
    int blk = (b < BREAL) ? li : li + NLAYERS;
    float4 wv = *(const float4*)(cw + (size_t)blk*DXBC*4 + c*4);
    float bias = cb[(size_t)blk*DXBC + c];
    int l0 = tl*CTL;
    size_t base = ((size_t)b*LSEQ)*DINP + DI + c;
    float xm3 = (l0 >= 3) ? bf2f(zxb[base + (size_t)(l0-3)*DINP]) : 0.f;
    float xm2 = (l0 >= 2) ? bf2f(zxb[base + (size_t)(l0-2)*DINP]) : 0.f;
    float xm1 = (l0 >= 1) ? bf2f(zxb[base + (size_t)(l0-1)*DINP]) : 0.f;
    for (int l = l0; l < l0 + CTL; l++){
        float xv = bf2f(zxb[base + (size_t)l*DINP]);
        float acc = bias + xm3*wv.x + xm2*wv.y + xm1*wv.z + xv*wv.w;
        xbcb[((size_t)(b*LSEQ)+l)*DXBC + c] = f2bf(siluf(acc));
        xm3 = xm2; xm2 = xm1; xm1 = xv;
    }
    if (ch == 0){
        #pragma unroll
        for (int it = 0; it < 2; it++){
            int e = threadIdx.x*2 + it;        // 0..511 = CTL x NHEADS
            int h = e & 7, dl = e >> 3;
            size_t bl = (size_t)b*LSEQ + l0 + dl;
            float raw = bf2f(zxb[bl*DINP + DI + DXBC + h]) + dtb[blk*NHEADS + h];
            float d = (raw > 20.f) ? raw : log1pf(__expf(raw));
            dtO[bl*NHEADS + h] = d;
            laO[bl*NHEADS + h] = -d*__expf(Al[blk*NHEADS + h]);
        }
    }
}

// ---------------- chunk pass 1 (MFMA, 4 heads/block): h_loc = (w*dt*x)^T @ B ----------------
__global__ __launch_bounds__(256) void k_chunk_state(const unsigned short* __restrict__ xbcb,
                                                     const float* __restrict__ dt, const float* __restrict__ la,
                                                     unsigned short* __restrict__ states, float* __restrict__ decp){
    __shared__ unsigned short sBT[DSZ][72];   // B^T: [n][j]
    __shared__ unsigned short sXT[HDIM][72];  // (dt*x*w)^T: [p][j]  (per-head, reused)
    __shared__ float sW[4][QCH];
    int bid = blockIdx.x;                     // BT*NCH*2
    int hg = bid & 1;
    int c  = (bid >> 1) & (NCH-1);
    int b  = bid >> 6;
    int t = threadIdx.x;
    int w = t >> 6, lane = t & 63, l15 = lane & 15, lg = lane >> 4;
    size_t bl0 = (size_t)b*LSEQ + c*QCH;

    // per-wave cumsum: wave w owns head hg*4+w
    {
        int h = hg*4 + w;
        float v = la[(bl0 + lane)*NHEADS + h];
        #pragma unroll
        for (int o = 1; o < 64; o <<= 1){
            float u = __shfl_up(v, o, 64);
            if (lane >= o) v += u;
        }
        float saQ = __shfl(v, 63, 64);
        float dtv = dt[(bl0 + lane)*NHEADS + h];
        sW[w][lane] = dtv * __expf(saQ - v);
        if (lane == 63) decp[((size_t)b*NHEADS + h)*NCH + c] = __expf(v);
    }
    // stage B^T (scatter) : 64 rows(j) x 128 cols(n) -- shared by all heads
    #pragma unroll
    for (int it = 0; it < 4; it++){
        int e = t + 256*it;
        int j = e >> 4, n8 = (e & 15)*8;
        int4 v = *(const int4*)(xbcb + (bl0 + j)*DXBC + DI + n8);
        const unsigned short* pv = (const unsigned short*)&v;
        #pragma unroll
        for (int i = 0; i < 8; i++) sBT[n8+i][j] = pv[i];
    }
    __syncthreads();

    int p0 = (w >> 1)*32, n0 = (w & 1)*64;
    for (int hh = 0; hh < 4; hh++){
        int h = hg*4 + hh;
        // stage (w*dt*x)^T for this head
        #pragma unroll
        for (int it = 0; it < 4; it++){
            int e = t + 256*it;
            int j = e >> 4, p4 = (e & 15)*4;
            ushort4 v = *(const ushort4*)(xbcb + (bl0 + j)*DXBC + h*HDIM + p4);
            float s = sW[hh][j];
            sXT[p4+0][j] = f2bf(bf2f(v.x)*s);
            sXT[p4+1][j] = f2bf(bf2f(v.y)*s);
            sXT[p4+2][j] = f2bf(bf2f(v.z)*s);
            sXT[p4+3][j] = f2bf(bf2f(v.w)*s);
        }
        __syncthreads();
        f32x4 acc[2][4];
        #pragma unroll
        for (int mi = 0; mi < 2; mi++)
            #pragma unroll
            for (int ni = 0; ni < 4; ni++) acc[mi][ni] = (f32x4){0.f,0.f,0.f,0.f};
        #pragma unroll
        for (int kk = 0; kk < 2; kk++){
            short8b a[2], bb[4];
            #pragma unroll
            for (int mi = 0; mi < 2; mi++) a[mi]  = *(const short8b*)&sXT[p0 + mi*16 + l15][kk*32 + lg*8];
            #pragma unroll
            for (int ni = 0; ni < 4; ni++) bb[ni] = *(const short8b*)&sBT[n0 + ni*16 + l15][kk*32 + lg*8];
            #pragma unroll
            for (int mi = 0; mi < 2; mi++)
                #pragma unroll
                for (int ni = 0; ni < 4; ni++)
                    acc[mi][ni] = __builtin_amdgcn_mfma_f32_16x16x32_bf16(a[mi], bb[ni], acc[mi][ni], 0, 0, 0);
        }
        unsigned short* sp = states + (((size_t)b*NHEADS + h)*NCH + c)*(HDIM*DSZ);
        #pragma unroll
        for (int mi = 0; mi < 2; mi++)
            #pragma unroll
            for (int ni = 0; ni < 4; ni++)
                #pragma unroll
                for (int r = 0; r < 4; r++){
                    int p = p0 + mi*16 + lg*4 + r;
                    int n = n0 + ni*16 + l15;
                    sp[(size_t)p*DSZ + n] = f2bf(acc[mi][ni][r]);
                }
        __syncthreads();
    }
}

// ---------------- pass 2: sequential combine across chunks (bf16 storage, f32 accum) ----------------
__global__ __launch_bounds__(256) void k_scan2(unsigned short* __restrict__ states, const float* __restrict__ decp){
    int bh = blockIdx.x >> 3, slice = blockIdx.x & 7;
    int t = threadIdx.x;
    size_t base = (size_t)bh*NCH*(HDIM*DSZ) + slice*1024 + t*4;
    float H0=0.f, H1=0.f, H2=0.f, H3=0.f;
    for (int c = 0; c < NCH; c++){
        float P = decp[bh*NCH + c];
        unsigned short* sp = states + base + (size_t)c*(HDIM*DSZ);
        ushort4 S = *(ushort4*)sp;
        ushort4 Hw;
        Hw.x = f2bf(H0); Hw.y = f2bf(H1); Hw.z = f2bf(H2); Hw.w = f2bf(H3);
        *(ushort4*)sp = Hw;
        H0 = fmaf(H0, P, bf2f(S.x));
        H1 = fmaf(H1, P, bf2f(S.y));
        H2 = fmaf(H2, P, bf2f(S.z));
        H3 = fmaf(H3, P, bf2f(S.w));
    }
}

// ---------------- chunk pass 3 (MFMA, 4 heads/block): Y = mask(C@B^T)@dtX + diag(exp(sa))*(C@h^T) + D*x ----------------
__global__ __launch_bounds__(256) void k_chunk_y(const unsigned short* __restrict__ xbcb,
                                                 const float* __restrict__ dt, const float* __restrict__ la,
                                                 const unsigned short* __restrict__ states,
                                                 const float* __restrict__ Dp, int li,
                                                 unsigned short* __restrict__ y){
    __shared__ unsigned short sB_[QCH][136];   // B rows [j][n] (shared across heads)
    __shared__ unsigned short sC_[QCH][136];   // C rows [i][n] (shared across heads)
    __shared__ unsigned short sS[QCH][72];     // masked S [i][j] (per-head)
    __shared__ unsigned short sXT[HDIM][72];   // (dt*x)^T [p][j] (per-head)
    __shared__ unsigned short sH[HDIM][136];   // h_in rows [p][n] (per-head)
    __shared__ float sSa[4][QCH];
    __shared__ float sDt[4][QCH];
    int bid = blockIdx.x;                      // BT*NCH*2
    int hg = bid & 1;
    int c  = (bid >> 1) & (NCH-1);
    int b  = bid >> 6;
    int blk = (b < BREAL) ? li : li + NLAYERS;
    int t = threadIdx.x;
    int w = t >> 6, lane = t & 63, l15 = lane & 15, lg = lane >> 4;
    size_t bl0 = (size_t)b*LSEQ + c*QCH;

    // per-wave cumsum: wave w owns head hg*4+w
    {
        int h = hg*4 + w;
        float v = la[(bl0 + lane)*NHEADS + h];
        #pragma unroll
        for (int o = 1; o < 64; o <<= 1){
            float u = __shfl_up(v, o, 64);
            if (lane >= o) v += u;
        }
        sSa[w][lane] = v;
        sDt[w][lane] = dt[(bl0 + lane)*NHEADS + h];
    }
    // stage B, C rows (shared)
    #pragma unroll
    for (int it = 0; it < 4; it++){
        int e = t + 256*it;
        int j = e >> 4, n8 = (e & 15)*8;
        *(int4*)&sB_[j][n8] = *(const int4*)(xbcb + (bl0 + j)*DXBC + DI + n8);
        *(int4*)&sC_[j][n8] = *(const int4*)(xbcb + (bl0 + j)*DXBC + DI + DSZ + n8);
    }
    __syncthreads();

    int i0 = (w >> 1)*32, q0 = (w & 1)*32;

    // SRAW = C @ B^T (K=128) once; persists in registers across head loop
    f32x4 accS[2][2];
    #pragma unroll
    for (int mi = 0; mi < 2; mi++)
        #pragma unroll
        for (int nj = 0; nj < 2; nj++) accS[mi][nj] = (f32x4){0.f,0.f,0.f,0.f};
    #pragma unroll
    for (int kk = 0; kk < 4; kk++){
        short8b a[2], bb[2];
        #pragma unroll
        for (int mi = 0; mi < 2; mi++) a[mi]  = *(const short8b*)&sC_[i0 + mi*16 + l15][kk*32 + lg*8];
        #pragma unroll
        for (int nj = 0; nj < 2; nj++) bb[nj] = *(const short8b*)&sB_[q0 + nj*16 + l15][kk*32 + lg*8];
        #pragma unroll
        for (int mi = 0; mi < 2; mi++)
            #pragma unroll
            for (int nj = 0; nj < 2; nj++)
                accS[mi][nj] = __builtin_amdgcn_mfma_f32_16x16x32_bf16(a[mi], bb[nj], accS[mi][nj], 0, 0, 0);
    }

    for (int hh = 0; hh < 4; hh++){
        int h = hg*4 + hh;
        // mask SRAW with per-head decay -> sS (bf16)
        #pragma unroll
        for (int mi = 0; mi < 2; mi++)
            #pragma unroll
            for (int nj = 0; nj < 2; nj++)
                #pragma unroll
                for (int r = 0; r < 4; r++){
                    int i = i0 + mi*16 + lg*4 + r;
                    int j = q0 + nj*16 + l15;
                    float wgt = (i >= j) ? __expf(sSa[hh][i] - sSa[hh][j]) : 0.f;
                    sS[i][j] = f2bf(accS[mi][nj][r] * wgt);
                }
        // stage (dt*x)^T and h_in for this head
        #pragma unroll
        for (int it = 0; it < 4; it++){
            int e = t + 256*it;
            int j = e >> 4, p4 = (e & 15)*4;
            ushort4 v = *(const ushort4*)(xbcb + (bl0 + j)*DXBC + h*HDIM + p4);
            float s = sDt[hh][j];
            sXT[p4+0][j] = f2bf(bf2f(v.x)*s);
            sXT[p4+1][j] = f2bf(bf2f(v.y)*s);
            sXT[p4+2][j] = f2bf(bf2f(v.z)*s);
            sXT[p4+3][j] = f2bf(bf2f(v.w)*s);
        }
        {
            size_t sbase = (((size_t)b*NHEADS + h)*NCH + c)*(HDIM*DSZ);
            #pragma unroll
            for (int it = 0; it < 4; it++){
                int e = t + 256*it;
                int p = e >> 4, n8 = (e & 15)*8;
                *(int4*)&sH[p][n8] = *(const int4*)(states + sbase + (size_t)p*DSZ + n8);
            }
        }
        __syncthreads();

        // Y_intra = S @ dtX (K=64); Y_inter = C @ h^T (K=128)
        f32x4 accY[2][2], accI[2][2];
        #pragma unroll
        for (int mi = 0; mi < 2; mi++)
            #pragma unroll
            for (int nj = 0; nj < 2; nj++){ accY[mi][nj] = (f32x4){0.f,0.f,0.f,0.f}; accI[mi][nj] = (f32x4){0.f,0.f,0.f,0.f}; }
        #pragma unroll
        for (int kk = 0; kk < 2; kk++){
            short8b a[2], bb[2];
            #pragma unroll
            for (int mi = 0; mi < 2; mi++) a[mi]  = *(const short8b*)&sS[i0 + mi*16 + l15][kk*32 + lg*8];
            #pragma unroll
            for (int nj = 0; nj < 2; nj++) bb[nj] = *(const short8b*)&sXT[q0 + nj*16 + l15][kk*32 + lg*8];
            #pragma unroll
            for (int mi = 0; mi < 2; mi++)
                #pragma unroll
                for (int nj = 0; nj < 2; nj++)
                    accY[mi][nj] = __builtin_amdgcn_mfma_f32_16x16x32_bf16(a[mi], bb[nj], accY[mi][nj], 0, 0, 0);
        }
        #pragma unroll
        for (int kk = 0; kk < 4; kk++){
            short8b a[2], bb[2];
            #pragma unroll
            for (int mi = 0; mi < 2; mi++) a[mi]  = *(const short8b*)&sC_[i0 + mi*16 + l15][kk*32 + lg*8];
            #pragma unroll
            for (int nj = 0; nj < 2; nj++) bb[nj] = *(const short8b*)&sH[q0 + nj*16 + l15][kk*32 + lg*8];
            #pragma unroll
            for (int mi = 0; mi < 2; mi++)
                #pragma unroll
                for (int nj = 0; nj < 2; nj++)
                    accI[mi][nj] = __builtin_amdgcn_mfma_f32_16x16x32_bf16(a[mi], bb[nj], accI[mi][nj], 0, 0, 0);
        }

        float dD = Dp[blk*NHEADS + h];
        #pragma unroll
        for (int mi = 0; mi < 2; mi++)
            #pragma unroll
            for (int r = 0; r < 4; r++){
                int i = i0 + mi*16 + lg*4 + r;
                float ei = __expf(sSa[hh][i]);
                #pragma unroll
                for (int nj = 0; nj < 2; nj++){
                    int p = q0 + nj*16 + l15;
                    float xh = bf2f(xbcb[(bl0 + i)*DXBC + h*HDIM + p]);
                    y[(bl0 + i)*DI + h*HDIM + p] = f2bf(accY[mi][nj][r] + ei*accI[mi][nj][r] + dD*xh);
                }
            }
        __syncthreads();
    }
}

// ---------------- gated rmsnorm: g = rmsnorm(y * silu(z)) * gw -> bf16 ----------------
__global__ __launch_bounds__(256) void k_gatenorm(const unsigned short* __restrict__ y, const unsigned short* __restrict__ zxb,
                                                  const float* __restrict__ gw, int li,
                                                  unsigned short* __restrict__ yb){
    int wid  = (blockIdx.x*256 + threadIdx.x) >> 6;
    int lane = threadIdx.x & 63;
    int b = wid / LSEQ;
    int blk = (b < BREAL) ? li : li + NLAYERS;
    const unsigned short* yr = y + (size_t)wid*DI;
    const unsigned short* zr = zxb + (size_t)wid*DINP;
    ushort4 yu0 = *(const ushort4*)(yr + lane*4);
    ushort4 yu1 = *(const ushort4*)(yr + 256 + lane*4);
    ushort4 zu0 = *(const ushort4*)(zr + lane*4);
    ushort4 zu1 = *(const ushort4*)(zr + 256 + lane*4);
    float4 v0, v1;
    v0.x = bf2f(yu0.x)*siluf(bf2f(zu0.x)); v0.y = bf2f(yu0.y)*siluf(bf2f(zu0.y));
    v0.z = bf2f(yu0.z)*siluf(bf2f(zu0.z)); v0.w = bf2f(yu0.w)*siluf(bf2f(zu0.w));
    v1.x = bf2f(yu1.x)*siluf(bf2f(zu1.x)); v1.y = bf2f(yu1.y)*siluf(bf2f(zu1.y));
    v1.z = bf2f(yu1.z)*siluf(bf2f(zu1.z)); v1.w = bf2f(yu1.w)*siluf(bf2f(zu1.w));
    float ss = v0.x*v0.x + v0.y*v0.y + v0.z*v0.z + v0.w*v0.w
             + v1.x*v1.x + v1.y*v1.y + v1.z*v1.z + v1.w*v1.w;
    #pragma unroll
    for (int o = 32; o >= 1; o >>= 1) ss += __shfl_xor(ss, o, 64);
    float sc = rsqrtf(ss*(1.f/DI) + EPSF);
    const float4* w4 = (const float4*)(gw + (size_t)blk*DI);
    float4 w0 = w4[lane], w1 = w4[64 + lane];
    ushort4 o0, o1;
    o0.x = f2bf(v0.x*sc*w0.x); o0.y = f2bf(v0.y*sc*w0.y); o0.z = f2bf(v0.z*sc*w0.z); o0.w = f2bf(v0.w*sc*w0.w);
    o1.x = f2bf(v1.x*sc*w1.x); o1.y = f2bf(v1.y*sc*w1.y); o1.z = f2bf(v1.z*sc*w1.z); o1.w = f2bf(v1.w*sc*w1.w);
    *(ushort4*)(yb + (size_t)wid*DI + lane*4)       = o0;
    *(ushort4*)(yb + (size_t)wid*DI + 256 + lane*4) = o1;
}

// ---------------- final: out = RES_fwd + flip(RES_bwd) ----------------
__global__ __launch_bounds__(256) void k_final(const float* __restrict__ res, float* __restrict__ out){
    int i = blockIdx.x*256 + threadIdx.x;
    int d4 = i & 63;
    int t  = i >> 6;
    int l = t % LSEQ, b = t / LSEQ;
    size_t fi = ((size_t)(b*LSEQ) + l)*(DM/4) + d4;
    size_t bi = ((size_t)((b+BREAL)*LSEQ) + (LSEQ-1-l))*(DM/4) + d4;
    float4 r1 = ((const float4*)res)[fi];
    float4 r2 = ((const float4*)res)[bi];
    float4 o;
    o.x = r1.x + r2.x;
    o.y = r1.y + r2.y;
    o.z = r1.z + r2.z;
    o.w = r1.w + r2.w;
    ((float4*)out)[i] = o;
}

extern "C" void kernel_launch(void* const* d_in, const int* in_sizes, int n_in,
                              void* d_out, int out_size, void* d_ws, size_t ws_size,
                              hipStream_t stream){
    const float* x   = (const float*)d_in[0];
    const float* nw  = (const float*)d_in[1];
    const float* Wi  = (const float*)d_in[2];
    const float* cw  = (const float*)d_in[3];
    const float* cb  = (const float*)d_in[4];
    const float* dtb = (const float*)d_in[5];
    const float* Al  = (const float*)d_in[6];
    const float* Dp  = (const float*)d_in[7];
    const float* gw  = (const float*)d_in[8];
    const float* Wo  = (const float*)d_in[9];
    float* out = (float*)d_out;

    // ---- workspace layout (~154 MiB) ----
    size_t off = 0;
    auto alloc = [&](size_t bytes){ void* p = (char*)d_ws + off; off += (bytes + 255) & ~(size_t)255; return p; };
    float* RES    = (float*)alloc((size_t)BT*LSEQ*DM*4);                        // 16 MiB, maintained by out_proj
    unsigned short* STATES = (unsigned short*)alloc((size_t)BT*NHEADS*NCH*HDIM*DSZ*2); // 32 MiB bf16
    unsigned short* YGB = (unsigned short*)alloc((size_t)BT*LSEQ*DI*2);         // 16 MiB (UBUF aliases)
    unsigned short* UBUF = YGB;
    unsigned short* ZXB = (unsigned short*)alloc((size_t)BT*LSEQ*DINP*2);       // 40.25 MiB bf16
    unsigned short* XBC = (unsigned short*)alloc((size_t)BT*LSEQ*DXBC*2);       // 24 MiB bf16
    float* DT     = (float*)alloc((size_t)BT*LSEQ*NHEADS*4);
    float* LA     = (float*)alloc((size_t)BT*LSEQ*NHEADS*4);
    unsigned short* YG = (unsigned short*)alloc((size_t)BT*LSEQ*DI*2);          // 16 MiB bf16
    float* DECP   = (float*)alloc((size_t)BT*NHEADS*NCH*4);
    unsigned short* WiT = (unsigned short*)alloc((size_t)2*NLAYERS*NINP_PAD*DM*2); // 5.5 MiB
    unsigned short* WoT = (unsigned short*)alloc((size_t)2*NLAYERS*DM*DI*2);       // 2 MiB
    (void)ws_size; (void)in_sizes; (void)n_in; (void)out_size;

    k_prep<<<(BT*LSEQ*DM/4)/256, 256, 0, stream>>>(x, RES);
    k_wtrans<<<dim3(NINP_PAD/32, DM/32, 2*NLAYERS), 256, 0, stream>>>(Wi, WiT, DM, DINP, NINP_PAD);
    k_wtrans<<<dim3(DM/32, DI/32, 2*NLAYERS), 256, 0, stream>>>(Wo, WoT, DI, DM, DM);

    for (int li = 0; li < NLAYERS; li++){
        k_resnorm<<<(BT*LSEQ)/4, 256, 0, stream>>>(RES, nw, li, UBUF);
        // in_proj: (BT*L x 256) @ (256 x 1288) -> bf16, 128x128 tiles BK=32 (nwg = 1408, %8==0)
        k_gemm_mfma<<<dim3(NINP_PAD/128, (BT*LSEQ)/128), 256, 0, stream>>>(
            UBUF, WiT + (size_t)li*NINP_PAD*DM, DM, DINP,
            (size_t)NLAYERS*NINP_PAD*DM, BREAL*LSEQ, nullptr, ZXB, 1);
        k_conv2<<<BT*(LSEQ/CTL)*3, 256, 0, stream>>>(ZXB, cw, cb, dtb, Al, li, XBC, DT, LA);
        k_chunk_state<<<BT*NCH*2, 256, 0, stream>>>(XBC, DT, LA, STATES, DECP);
        k_scan2<<<BT*NHEADS*8, 256, 0, stream>>>(STATES, DECP);
        k_chunk_y<<<BT*NCH*2, 256, 0, stream>>>(XBC, DT, LA, STATES, Dp, li, YG);
        k_gatenorm<<<(BT*LSEQ)/4, 256, 0, stream>>>(YG, ZXB, gw, li, YGB);
        // out_proj: (BT*L x 512) @ (512 x 256), RES += result (nwg = 256, %8==0)
        k_gemm_mfma<<<dim3(DM/128, (BT*LSEQ)/128), 256, 0, stream>>>(
            YGB, WoT + (size_t)li*DM*DI, DI, DM,
            (size_t)NLAYERS*DM*DI, BREAL*LSEQ, RES, nullptr, 2);
    }
    k_final<<<(BREAL*LSEQ*DM/4)/256, 256, 0, stream>>>(RES, out);
}